// Round 6
// baseline (504.895 us; speedup 1.0000x reference)
//
#include <hip/hip_runtime.h>
#include <hip/hip_fp16.h>
#include <math.h>

#define NANG 9
#define SS 16
#define NPIX 256
#define WSH 72                 // window row stride in half2 pairs; lanes tile banks 2-way
#define WROWS 27               // rows needed per sub-row block (8 by + 17 tap span + pads)
#define WINSZH (WROWS * WSH)   // 1944 pair-dwords = 7776 B
#define FLTMAX_BITS 0x7F7FFFFFu
#define PART_BYTES 16384       // 4096 float partials at ws offset 0

// 16B per (angle,pixel):
//  .x = half2 (ewx0, ewx1)           x-weights, block-validity folded in
//  .y = half2 (-s*ewy0, -s*ewy1)     NEGATED y-weights pre-scaled by s = sqrt(m/msum)
//  .z = f32 s
//  .w = (y0+1)*WSH + (x0+1)          tap offset; buffer row = by + y0 + 1 by construction

__global__ __launch_bounds__(256) void build_table(uint4* __restrict__ tbl)
{
    __shared__ float red[256];
    const int p  = threadIdx.x;
    const int px = p & 15, py = p >> 4;
    for (int a = 0; a < NANG; ++a) {
        double t  = (double)(a - 4) * 0.017453292519943295; // deg2rad
        double ca = cos(t), sa = sin(t);
        float sx = (float)(ca * px - sa * py + (1.0 - ca) * 8.0 + sa * 8.0);
        float sy = (float)(sa * px + ca * py - sa * 8.0 + (1.0 - ca) * 8.0);
        float x0f = floorf(sx), y0f = floorf(sy);
        int   x0  = (int)x0f,   y0  = (int)y0f;
        float wx1 = sx - x0f, wx0 = 1.0f - wx1;
        float wy1 = sy - y0f, wy0 = 1.0f - wy1;
        float ewx0 = (x0 >= 0 && x0 < SS)         ? wx0 : 0.0f;
        float ewx1 = (x0 + 1 >= 0 && x0 + 1 < SS) ? wx1 : 0.0f;
        float ewy0 = (y0 >= 0 && y0 < SS)         ? wy0 : 0.0f;
        float ewy1 = (y0 + 1 >= 0 && y0 + 1 < SS) ? wy1 : 0.0f;
        float m = (ewx0 + ewx1) * (ewy0 + ewy1);

        red[p] = m;
        __syncthreads();
        for (int s = 128; s > 0; s >>= 1) {
            if (p < s) red[p] += red[p + s];
            __syncthreads();
        }
        float msum = red[0];
        __syncthreads();

        float sc = sqrtf(m / msum);
        x0 = max(-1, min(15, x0));   // LDS bounds safety (weights encode validity)
        y0 = max(-1, min(15, y0));
        uint4 e;
        e.x = (unsigned)__half_as_ushort(__float2half(ewx0)) |
              ((unsigned)__half_as_ushort(__float2half(ewx1)) << 16);
        e.y = (unsigned)__half_as_ushort(__float2half(-sc * ewy0)) |
              ((unsigned)__half_as_ushort(__float2half(-sc * ewy1)) << 16);
        e.z = __float_as_uint(sc);
        e.w = (unsigned)((y0 + 1) * WSH + (x0 + 1));
        tbl[a * NPIX + p] = e;
    }
}

// butterfly-sum across 64 lanes on the VALU pipe; full sum lands in lane 63
#define DPPADD(v, ctrl, rmask)                                                   \
    v += __int_as_float(__builtin_amdgcn_update_dpp(                             \
            0, __float_as_int(v), ctrl, rmask, 0xf, true))

// Load one pair-row per k and packed-x-interp into h[k][0..NP-1] (half2 pairs).
template<int NP>
__device__ __forceinline__ void rowload(const __half2* __restrict__ winh,
                                        int (&addr)[4],
                                        const __half2 (&wx0)[4], const __half2 (&wx1)[4],
                                        __half2 (&h)[4][NP])
{
    #pragma unroll
    for (int k = 0; k < 4; ++k) {
        __half2 d[2 * NP];
        #pragma unroll
        for (int j = 0; j < 2 * NP; ++j) d[j] = winh[addr[k] + j];  // ds_read2_b32
        #pragma unroll
        for (int c = 0; c < NP; ++c)
            h[k][c] = __hfma2(wx1[k], d[2 * c + 1], __hmul2(wx0[k], d[2 * c]));
        addr[k] += WSH;
    }
}

// One by-step: packed y-interp + square-acc (2 bx per op), unpack, DPP-reduce,
// min over the (compile-time) valid bx count, atomicMin into submin[subcol].
template<int NP>
__device__ __forceinline__ void bystep(const __half2 (&hp)[4][NP], const __half2 (&hc)[4][NP],
                                       const __half2 (&wy0n)[4], const __half2 (&wy1n)[4],
                                       const __half2 (&r1s)[4],
                                       unsigned* __restrict__ sm, int lane)
{
    __half2 acc[NP];
    #pragma unroll
    for (int c = 0; c < NP; ++c) acc[c] = __floats2half2_rn(0.f, 0.f);
    #pragma unroll
    for (int k = 0; k < 4; ++k) {
        #pragma unroll
        for (int c = 0; c < NP; ++c) {
            __half2 e = __hfma2(wy0n[k], hp[k][c], r1s[k]);  // r1s - wys0*hp
            e = __hfma2(wy1n[k], hc[k][c], e);               //     - wys1*hc
            acc[c] = __hfma2(e, e, acc[c]);
        }
    }
    constexpr int NJ = 2 * NP - 1;     // valid bx count: NP=5 -> 9, NP=3 -> 5
    float v[NJ];
    #pragma unroll
    for (int c = 0; c < NP; ++c) {
        v[2 * c] = __low2float(acc[c]);
        if (2 * c + 1 < NJ) v[2 * c + 1] = __high2float(acc[c]);
    }
    #pragma unroll
    for (int j = 0; j < NJ; ++j) {
        DPPADD(v[j], 0xB1,  0xf);   // xor 1
        DPPADD(v[j], 0x4E,  0xf);   // xor 2
        DPPADD(v[j], 0x141, 0xf);   // row_half_mirror (xor 4)
        DPPADD(v[j], 0x140, 0xf);   // row_mirror      (xor 8)
        DPPADD(v[j], 0x142, 0xa);   // row_bcast:15 -> rows 1,3
        DPPADD(v[j], 0x143, 0xc);   // row_bcast:31 -> rows 2,3
    }
    if (lane == 63) {
        float best = v[0];
        #pragma unroll
        for (int j = 1; j < NJ; ++j) best = fminf(best, v[j]);
        atomicMin(sm, __float_as_uint(best));   // scores >= 0: uint order == float order
    }
}

template<int NBY, int NP>
__device__ __forceinline__ void proc(const __half2* __restrict__ winh, int (&addr)[4],
                                     const __half2 (&wx0)[4], const __half2 (&wx1)[4],
                                     const __half2 (&wy0n)[4], const __half2 (&wy1n)[4],
                                     const __half2 (&r1s)[4],
                                     unsigned* __restrict__ sm, int lane)
{
    __half2 hA[4][NP], hB[4][NP];
    rowload<NP>(winh, addr, wx0, wx1, hA);
    #pragma unroll
    for (int by = 0; by < NBY + 1; by += 2) {
        rowload<NP>(winh, addr, wx0, wx1, hB);
        bystep<NP>(hA, hB, wy0n, wy1n, r1s, sm, lane);
        if (by + 1 < NBY + 1) {
            rowload<NP>(winh, addr, wx0, wx1, hA);
            bystep<NP>(hB, hA, wy0n, wy1n, r1s, sm, lane);
        }
    }
}

// 4 blocks per image: block g owns sub-row g (4 subs x 9 angles = 36 items,
// 9 per wave). Small 27-row window -> 7.8 KB LDS -> full occupancy.
__global__ __launch_bounds__(256, 8) void randip_main(const float* __restrict__ fm1,
                                                      const float* __restrict__ fm2,
                                                      const uint4* __restrict__ gt,
                                                      float* __restrict__ part)
{
    __shared__ __half2 winh[WINSZH];    // 7776 B: pair c = (w[c-1], w[c]), f16
    __shared__ unsigned submin[4];

    const int bi   = blockIdx.x;
    const int b    = bi >> 2;
    const int g    = bi & 3;
    const int tid  = threadIdx.x;
    const int wave = tid >> 6;
    const int lane = tid & 63;

    const int sub_y  = g << 4;
    const int y_lo   = max(sub_y - 4, 0);
    const int nby    = min(sub_y + 4, 48) - y_lo;   // 4 (g=0,3) or 8 (g=1,2)
    const int base_y = y_lo - 1;                    // buffer row = global row - base_y

    for (int i = tid; i < WINSZH; i += 256) winh[i] = __floats2half2_rn(0.f, 0.f);
    if (tid < 4) submin[tid] = FLTMAX_BITS;
    __syncthreads();

    // fill pair-window: buffer (r, c) = (img2[gr][c-1], img2[gr][c]), gr = base_y + r
    const float* img2 = fm2 + (size_t)b * 4096;
    for (int i = tid; i < WROWS * 65; i += 256) {
        int r = i / 65, c = i - r * 65;
        int gr = base_y + r;
        if (gr >= 0 && gr <= 63) {
            float lo = (c >= 1)  ? img2[gr * 64 + c - 1] : 0.f;
            float hi = (c <= 63) ? img2[gr * 64 + c]     : 0.f;
            winh[r * WSH + c] = __floats2half2_rn(lo, hi);
        }
    }
    __syncthreads();

    const float* img1 = fm1 + (size_t)b * 4096;

    int a_cur = -1;
    __half2 wx0[4], wx1[4], wy0n[4], wy1n[4], r1s[4];
    float   sca[4];
    int     off[4];

    for (int i = wave * 9; i < wave * 9 + 9; ++i) {   // 36 items: (a, subcol)
        const int a = i >> 2, sc = i & 3;
        if (a != a_cur) {                     // ~3 reloads per wave, coalesced b128
            a_cur = a;
            const uint4* tp = gt + a * NPIX + lane;
            #pragma unroll
            for (int k = 0; k < 4; ++k) {
                uint4 te = tp[64 * k];
                __half2 X = *(const __half2*)&te.x;
                __half2 Y = *(const __half2*)&te.y;
                wx0[k]  = __half2half2(__low2half(X));
                wx1[k]  = __half2half2(__high2half(X));
                wy0n[k] = __half2half2(__low2half(Y));
                wy1n[k] = __half2half2(__high2half(Y));
                sca[k]  = __uint_as_float(te.z);
                off[k]  = (int)te.w;
            }
        }
        const int sub_x = sc << 4;
        const int x_lo = max(sub_x - 4, 0);
        const int nvx = min(sub_x + 4, 48) - x_lo;   // 4 (sc=0,3) or 8 (sc=1,2)

        const float* r1p = img1 + (sub_y + (lane >> 4)) * 64 + sub_x + (lane & 15);
        #pragma unroll
        for (int k = 0; k < 4; ++k)
            r1s[k] = __float2half2_rn(sca[k] * r1p[k * 4 * 64]);

        int addr[4];
        #pragma unroll
        for (int k = 0; k < 4; ++k) addr[k] = off[k] + x_lo;   // row by+y0+1, col x_lo+x0+1

        unsigned* sm = &submin[sc];
        if (nby == 8) {
            if (nvx == 8) proc<8, 5>(winh, addr, wx0, wx1, wy0n, wy1n, r1s, sm, lane);
            else          proc<8, 3>(winh, addr, wx0, wx1, wy0n, wy1n, r1s, sm, lane);
        } else {
            if (nvx == 8) proc<4, 5>(winh, addr, wx0, wx1, wy0n, wy1n, r1s, sm, lane);
            else          proc<4, 3>(winh, addr, wx0, wx1, wy0n, wy1n, r1s, sm, lane);
        }
    }
    __syncthreads();

    if (tid == 0) {
        float t = 0.0f;
        #pragma unroll
        for (int s = 0; s < 4; ++s) t += __uint_as_float(submin[s]);
        part[b * 4 + g] = t;
    }
}

__global__ __launch_bounds__(256) void reduce_out(const float* __restrict__ part,
                                                  float* __restrict__ out, int nb)
{
    int i = blockIdx.x * 256 + threadIdx.x;
    if (i < nb)
        out[i] = ((part[4 * i] + part[4 * i + 1]) + part[4 * i + 2]) + part[4 * i + 3];
}

extern "C" void kernel_launch(void* const* d_in, const int* in_sizes, int n_in,
                              void* d_out, int out_size, void* d_ws, size_t ws_size,
                              hipStream_t stream)
{
    const float* fm1 = (const float*)d_in[0];
    const float* fm2 = (const float*)d_in[1];
    float* out  = (float*)d_out;
    float* part = (float*)d_ws;                                // 16 KB partials
    uint4* tbl  = (uint4*)((char*)d_ws + PART_BYTES);          // + 36,864 B table

    const int nb = in_sizes[0] >> 12;   // 1024 images of 64*64

    hipLaunchKernelGGL(build_table, dim3(1), dim3(256), 0, stream, tbl);
    hipLaunchKernelGGL(randip_main, dim3(4 * nb), dim3(256), 0, stream,
                       fm1, fm2, tbl, part);
    hipLaunchKernelGGL(reduce_out, dim3((nb + 255) / 256), dim3(256), 0, stream,
                       part, out, nb);
}

// Round 7
// 428.191 us; speedup vs baseline: 1.1791x; 1.1791x over previous
//
#include <hip/hip_runtime.h>
#include <hip/hip_fp16.h>
#include <math.h>

#define NANG 9
#define SS 16
#define NPIX 256
#define WSH 72                 // window row stride in half2 pairs; lanes tile banks 2-way
#define WROWS 27               // rows needed per sub-row block (8 by + 17 tap span + pads)
#define WINSZH (WROWS * WSH)   // 1944 pair-dwords = 7776 B
#define FLTMAX_BITS 0x7F7FFFFFu
#define PART_BYTES 16384       // 4096 float partials at ws offset 0

// 16B per (angle,pixel):
//  .x = half2 (ewx0, ewx1)           x-weights, block-validity folded in
//  .y = half2 (-s*ewy0, -s*ewy1)     NEGATED y-weights pre-scaled by s = sqrt(m/msum)
//  .z = f32 s
//  .w = (y0+1)*WSH + (x0+1)          tap offset; buffer row = by + y0 + 1 by construction

__global__ __launch_bounds__(256) void build_table(uint4* __restrict__ tbl)
{
    __shared__ float red[256];
    const int p  = threadIdx.x;
    const int px = p & 15, py = p >> 4;
    for (int a = 0; a < NANG; ++a) {
        double t  = (double)(a - 4) * 0.017453292519943295; // deg2rad
        double ca = cos(t), sa = sin(t);
        float sx = (float)(ca * px - sa * py + (1.0 - ca) * 8.0 + sa * 8.0);
        float sy = (float)(sa * px + ca * py - sa * 8.0 + (1.0 - ca) * 8.0);
        float x0f = floorf(sx), y0f = floorf(sy);
        int   x0  = (int)x0f,   y0  = (int)y0f;
        float wx1 = sx - x0f, wx0 = 1.0f - wx1;
        float wy1 = sy - y0f, wy0 = 1.0f - wy1;
        float ewx0 = (x0 >= 0 && x0 < SS)         ? wx0 : 0.0f;
        float ewx1 = (x0 + 1 >= 0 && x0 + 1 < SS) ? wx1 : 0.0f;
        float ewy0 = (y0 >= 0 && y0 < SS)         ? wy0 : 0.0f;
        float ewy1 = (y0 + 1 >= 0 && y0 + 1 < SS) ? wy1 : 0.0f;
        float m = (ewx0 + ewx1) * (ewy0 + ewy1);

        red[p] = m;
        __syncthreads();
        for (int s = 128; s > 0; s >>= 1) {
            if (p < s) red[p] += red[p + s];
            __syncthreads();
        }
        float msum = red[0];
        __syncthreads();

        float sc = sqrtf(m / msum);
        x0 = max(-1, min(15, x0));   // LDS bounds safety (weights encode validity)
        y0 = max(-1, min(15, y0));
        uint4 e;
        e.x = (unsigned)__half_as_ushort(__float2half(ewx0)) |
              ((unsigned)__half_as_ushort(__float2half(ewx1)) << 16);
        e.y = (unsigned)__half_as_ushort(__float2half(-sc * ewy0)) |
              ((unsigned)__half_as_ushort(__float2half(-sc * ewy1)) << 16);
        e.z = __float_as_uint(sc);
        e.w = (unsigned)((y0 + 1) * WSH + (x0 + 1));
        tbl[a * NPIX + p] = e;
    }
}

// butterfly-sum across 64 lanes on the VALU pipe; full sum lands in lane 63
#define DPPADD(v, ctrl, rmask)                                                   \
    v += __int_as_float(__builtin_amdgcn_update_dpp(                             \
            0, __float_as_int(v), ctrl, rmask, 0xf, true))

// Load one pair-row per k and packed-x-interp into h[k][0..NP-1] (half2 pairs).
template<int NP>
__device__ __forceinline__ void rowload(const __half2* __restrict__ winh,
                                        int (&addr)[4],
                                        const __half2 (&wx0)[4], const __half2 (&wx1)[4],
                                        __half2 (&h)[4][NP])
{
    #pragma unroll
    for (int k = 0; k < 4; ++k) {
        __half2 d[2 * NP];
        #pragma unroll
        for (int j = 0; j < 2 * NP; ++j) d[j] = winh[addr[k] + j];  // ds_read2_b32
        #pragma unroll
        for (int c = 0; c < NP; ++c)
            h[k][c] = __hfma2(wx1[k], d[2 * c + 1], __hmul2(wx0[k], d[2 * c]));
        addr[k] += WSH;
    }
}

// One by-step: packed y-interp + square-acc (2 bx per op), unpack, DPP-reduce,
// min over the (compile-time) valid bx count, atomicMin into submin[subcol].
template<int NP>
__device__ __forceinline__ void bystep(const __half2 (&hp)[4][NP], const __half2 (&hc)[4][NP],
                                       const __half2 (&wy0n)[4], const __half2 (&wy1n)[4],
                                       const __half2 (&r1s)[4],
                                       unsigned* __restrict__ sm, int lane)
{
    __half2 acc[NP];
    #pragma unroll
    for (int c = 0; c < NP; ++c) acc[c] = __floats2half2_rn(0.f, 0.f);
    #pragma unroll
    for (int k = 0; k < 4; ++k) {
        #pragma unroll
        for (int c = 0; c < NP; ++c) {
            __half2 e = __hfma2(wy0n[k], hp[k][c], r1s[k]);  // r1s - wys0*hp
            e = __hfma2(wy1n[k], hc[k][c], e);               //     - wys1*hc
            acc[c] = __hfma2(e, e, acc[c]);
        }
    }
    constexpr int NJ = 2 * NP - 1;     // valid bx count: NP=5 -> 9, NP=3 -> 5
    float v[NJ];
    #pragma unroll
    for (int c = 0; c < NP; ++c) {
        v[2 * c] = __low2float(acc[c]);
        if (2 * c + 1 < NJ) v[2 * c + 1] = __high2float(acc[c]);
    }
    #pragma unroll
    for (int j = 0; j < NJ; ++j) {
        DPPADD(v[j], 0xB1,  0xf);   // xor 1
        DPPADD(v[j], 0x4E,  0xf);   // xor 2
        DPPADD(v[j], 0x141, 0xf);   // row_half_mirror (xor 4)
        DPPADD(v[j], 0x140, 0xf);   // row_mirror      (xor 8)
        DPPADD(v[j], 0x142, 0xa);   // row_bcast:15 -> rows 1,3
        DPPADD(v[j], 0x143, 0xc);   // row_bcast:31 -> rows 2,3
    }
    if (lane == 63) {
        float best = v[0];
        #pragma unroll
        for (int j = 1; j < NJ; ++j) best = fminf(best, v[j]);
        atomicMin(sm, __float_as_uint(best));   // scores >= 0: uint order == float order
    }
}

template<int NBY, int NP>
__device__ __forceinline__ void proc(const __half2* __restrict__ winh, int (&addr)[4],
                                     const __half2 (&wx0)[4], const __half2 (&wx1)[4],
                                     const __half2 (&wy0n)[4], const __half2 (&wy1n)[4],
                                     const __half2 (&r1s)[4],
                                     unsigned* __restrict__ sm, int lane)
{
    __half2 hA[4][NP], hB[4][NP];
    rowload<NP>(winh, addr, wx0, wx1, hA);
    #pragma unroll
    for (int by = 0; by < NBY + 1; by += 2) {
        rowload<NP>(winh, addr, wx0, wx1, hB);
        bystep<NP>(hA, hB, wy0n, wy1n, r1s, sm, lane);
        if (by + 1 < NBY + 1) {
            rowload<NP>(winh, addr, wx0, wx1, hA);
            bystep<NP>(hB, hA, wy0n, wy1n, r1s, sm, lane);
        }
    }
}

// 4 blocks per image: block g owns sub-row g (4 subs x 9 angles = 36 items,
// 9 per wave). Small 27-row window -> 7.8 KB LDS; default launch bounds so the
// allocator is free (52-64 VGPR -> no spill; 64 VGPR still allows 8 waves/SIMD).
__global__ __launch_bounds__(256) void randip_main(const float* __restrict__ fm1,
                                                   const float* __restrict__ fm2,
                                                   const uint4* __restrict__ gt,
                                                   float* __restrict__ part)
{
    __shared__ __half2 winh[WINSZH];    // 7776 B: pair c = (w[c-1], w[c]), f16
    __shared__ unsigned submin[4];

    const int bi   = blockIdx.x;
    const int b    = bi >> 2;
    const int g    = bi & 3;
    const int tid  = threadIdx.x;
    const int wave = tid >> 6;
    const int lane = tid & 63;

    const int sub_y  = g << 4;
    const int y_lo   = max(sub_y - 4, 0);
    const int nby    = min(sub_y + 4, 48) - y_lo;   // 4 (g=0,3) or 8 (g=1,2)
    const int base_y = y_lo - 1;                    // buffer row = global row - base_y

    for (int i = tid; i < WINSZH; i += 256) winh[i] = __floats2half2_rn(0.f, 0.f);
    if (tid < 4) submin[tid] = FLTMAX_BITS;
    __syncthreads();

    // fill pair-window: buffer (r, c) = (img2[gr][c-1], img2[gr][c]), gr = base_y + r
    const float* img2 = fm2 + (size_t)b * 4096;
    for (int i = tid; i < WROWS * 65; i += 256) {
        int r = i / 65, c = i - r * 65;
        int gr = base_y + r;
        if (gr >= 0 && gr <= 63) {
            float lo = (c >= 1)  ? img2[gr * 64 + c - 1] : 0.f;
            float hi = (c <= 63) ? img2[gr * 64 + c]     : 0.f;
            winh[r * WSH + c] = __floats2half2_rn(lo, hi);
        }
    }
    __syncthreads();

    const float* img1 = fm1 + (size_t)b * 4096;

    int a_cur = -1;
    __half2 wx0[4], wx1[4], wy0n[4], wy1n[4], r1s[4];
    float   sca[4];
    int     off[4];

    for (int i = wave * 9; i < wave * 9 + 9; ++i) {   // 36 items: (a, subcol)
        const int a = i >> 2, sc = i & 3;
        if (a != a_cur) {                     // ~3 reloads per wave, coalesced b128
            a_cur = a;
            const uint4* tp = gt + a * NPIX + lane;
            #pragma unroll
            for (int k = 0; k < 4; ++k) {
                uint4 te = tp[64 * k];
                __half2 X = *(const __half2*)&te.x;
                __half2 Y = *(const __half2*)&te.y;
                wx0[k]  = __half2half2(__low2half(X));
                wx1[k]  = __half2half2(__high2half(X));
                wy0n[k] = __half2half2(__low2half(Y));
                wy1n[k] = __half2half2(__high2half(Y));
                sca[k]  = __uint_as_float(te.z);
                off[k]  = (int)te.w;
            }
        }
        const int sub_x = sc << 4;
        const int x_lo = max(sub_x - 4, 0);
        const int nvx = min(sub_x + 4, 48) - x_lo;   // 4 (sc=0,3) or 8 (sc=1,2)

        const float* r1p = img1 + (sub_y + (lane >> 4)) * 64 + sub_x + (lane & 15);
        #pragma unroll
        for (int k = 0; k < 4; ++k)
            r1s[k] = __float2half2_rn(sca[k] * r1p[k * 4 * 64]);

        int addr[4];
        #pragma unroll
        for (int k = 0; k < 4; ++k) addr[k] = off[k] + x_lo;   // row by+y0+1, col x_lo+x0+1

        unsigned* sm = &submin[sc];
        if (nby == 8) {
            if (nvx == 8) proc<8, 5>(winh, addr, wx0, wx1, wy0n, wy1n, r1s, sm, lane);
            else          proc<8, 3>(winh, addr, wx0, wx1, wy0n, wy1n, r1s, sm, lane);
        } else {
            if (nvx == 8) proc<4, 5>(winh, addr, wx0, wx1, wy0n, wy1n, r1s, sm, lane);
            else          proc<4, 3>(winh, addr, wx0, wx1, wy0n, wy1n, r1s, sm, lane);
        }
    }
    __syncthreads();

    if (tid == 0) {
        float t = 0.0f;
        #pragma unroll
        for (int s = 0; s < 4; ++s) t += __uint_as_float(submin[s]);
        part[b * 4 + g] = t;
    }
}

__global__ __launch_bounds__(256) void reduce_out(const float* __restrict__ part,
                                                  float* __restrict__ out, int nb)
{
    int i = blockIdx.x * 256 + threadIdx.x;
    if (i < nb)
        out[i] = ((part[4 * i] + part[4 * i + 1]) + part[4 * i + 2]) + part[4 * i + 3];
}

extern "C" void kernel_launch(void* const* d_in, const int* in_sizes, int n_in,
                              void* d_out, int out_size, void* d_ws, size_t ws_size,
                              hipStream_t stream)
{
    const float* fm1 = (const float*)d_in[0];
    const float* fm2 = (const float*)d_in[1];
    float* out  = (float*)d_out;
    float* part = (float*)d_ws;                                // 16 KB partials
    uint4* tbl  = (uint4*)((char*)d_ws + PART_BYTES);          // + 36,864 B table

    const int nb = in_sizes[0] >> 12;   // 1024 images of 64*64

    hipLaunchKernelGGL(build_table, dim3(1), dim3(256), 0, stream, tbl);
    hipLaunchKernelGGL(randip_main, dim3(4 * nb), dim3(256), 0, stream,
                       fm1, fm2, tbl, part);
    hipLaunchKernelGGL(reduce_out, dim3((nb + 255) / 256), dim3(256), 0, stream,
                       part, out, nb);
}

// Round 8
// 351.949 us; speedup vs baseline: 1.4346x; 1.2166x over previous
//
#include <hip/hip_runtime.h>
#include <hip/hip_fp16.h>
#include <math.h>

#define NANG 9
#define SS 16
#define NPIX 256
#define WSH 72                 // window row stride in half2 pairs; lanes tile banks 2-way
#define NROWW 70
#define WINSZH (NROWW * WSH)   // 5040 pair-dwords = 20160 B
#define NITEM (NANG * 16)      // 144 (angle, sub) items per image
#define NWAVE 8                // 512-thread blocks -> 4 blocks/CU x 8 waves = 32 waves/CU
#define IPW (NITEM / NWAVE)    // 18 items per wave
#define FLTMAX_BITS 0x7F7FFFFFu

// 16B per (angle,pixel):
//  .x = half2 (ewx0, ewx1)           x-weights, block-validity folded in
//  .y = half2 (-s*ewy0, -s*ewy1)     NEGATED y-weights pre-scaled by s = sqrt(m/msum)
//  .z = f32 s
//  .w = (y0+1)*WSH + (x0+1)          tap offset within padded pair-window

__global__ __launch_bounds__(256) void build_table(uint4* __restrict__ tbl)
{
    __shared__ float red[256];
    const int p  = threadIdx.x;
    const int px = p & 15, py = p >> 4;
    for (int a = 0; a < NANG; ++a) {
        double t  = (double)(a - 4) * 0.017453292519943295; // deg2rad
        double ca = cos(t), sa = sin(t);
        float sx = (float)(ca * px - sa * py + (1.0 - ca) * 8.0 + sa * 8.0);
        float sy = (float)(sa * px + ca * py - sa * 8.0 + (1.0 - ca) * 8.0);
        float x0f = floorf(sx), y0f = floorf(sy);
        int   x0  = (int)x0f,   y0  = (int)y0f;
        float wx1 = sx - x0f, wx0 = 1.0f - wx1;
        float wy1 = sy - y0f, wy0 = 1.0f - wy1;
        float ewx0 = (x0 >= 0 && x0 < SS)         ? wx0 : 0.0f;
        float ewx1 = (x0 + 1 >= 0 && x0 + 1 < SS) ? wx1 : 0.0f;
        float ewy0 = (y0 >= 0 && y0 < SS)         ? wy0 : 0.0f;
        float ewy1 = (y0 + 1 >= 0 && y0 + 1 < SS) ? wy1 : 0.0f;
        float m = (ewx0 + ewx1) * (ewy0 + ewy1);

        red[p] = m;
        __syncthreads();
        for (int s = 128; s > 0; s >>= 1) {
            if (p < s) red[p] += red[p + s];
            __syncthreads();
        }
        float msum = red[0];
        __syncthreads();

        float sc = sqrtf(m / msum);
        x0 = max(-1, min(15, x0));   // LDS bounds safety (weights encode validity)
        y0 = max(-1, min(15, y0));
        uint4 e;
        e.x = (unsigned)__half_as_ushort(__float2half(ewx0)) |
              ((unsigned)__half_as_ushort(__float2half(ewx1)) << 16);
        e.y = (unsigned)__half_as_ushort(__float2half(-sc * ewy0)) |
              ((unsigned)__half_as_ushort(__float2half(-sc * ewy1)) << 16);
        e.z = __float_as_uint(sc);
        e.w = (unsigned)((y0 + 1) * WSH + (x0 + 1));
        tbl[a * NPIX + p] = e;
    }
}

// butterfly-sum across 64 lanes on the VALU pipe; full sum lands in lane 63
#define DPPADD(v, ctrl, rmask)                                                   \
    v += __int_as_float(__builtin_amdgcn_update_dpp(                             \
            0, __float_as_int(v), ctrl, rmask, 0xf, true))

// Load one pair-row per k and packed-x-interp into h[k][0..NP-1] (half2 pairs).
template<int NP>
__device__ __forceinline__ void rowload(const __half2* __restrict__ winh,
                                        int (&addr)[4],
                                        const __half2 (&wx0)[4], const __half2 (&wx1)[4],
                                        __half2 (&h)[4][NP])
{
    #pragma unroll
    for (int k = 0; k < 4; ++k) {
        __half2 d[2 * NP];
        #pragma unroll
        for (int j = 0; j < 2 * NP; ++j) d[j] = winh[addr[k] + j];  // ds_read2_b32
        #pragma unroll
        for (int c = 0; c < NP; ++c)
            h[k][c] = __hfma2(wx1[k], d[2 * c + 1], __hmul2(wx0[k], d[2 * c]));
        addr[k] += WSH;
    }
}

// One by-step: packed y-interp + square-acc (2 bx per op), unpack, DPP-reduce,
// min over the (compile-time) valid bx count, atomicMin into submin[sub].
template<int NP>
__device__ __forceinline__ void bystep(const __half2 (&hp)[4][NP], const __half2 (&hc)[4][NP],
                                       const __half2 (&wy0n)[4], const __half2 (&wy1n)[4],
                                       const __half2 (&r1s)[4],
                                       unsigned* __restrict__ sm, int lane)
{
    __half2 acc[NP];
    #pragma unroll
    for (int c = 0; c < NP; ++c) acc[c] = __floats2half2_rn(0.f, 0.f);
    #pragma unroll
    for (int k = 0; k < 4; ++k) {
        #pragma unroll
        for (int c = 0; c < NP; ++c) {
            __half2 e = __hfma2(wy0n[k], hp[k][c], r1s[k]);  // r1s - wys0*hp
            e = __hfma2(wy1n[k], hc[k][c], e);               //     - wys1*hc
            acc[c] = __hfma2(e, e, acc[c]);
        }
    }
    constexpr int NJ = 2 * NP - 1;     // valid bx count: NP=5 -> 9, NP=3 -> 5
    float v[NJ];
    #pragma unroll
    for (int c = 0; c < NP; ++c) {
        v[2 * c] = __low2float(acc[c]);
        if (2 * c + 1 < NJ) v[2 * c + 1] = __high2float(acc[c]);
    }
    #pragma unroll
    for (int j = 0; j < NJ; ++j) {
        DPPADD(v[j], 0xB1,  0xf);   // xor 1
        DPPADD(v[j], 0x4E,  0xf);   // xor 2
        DPPADD(v[j], 0x141, 0xf);   // row_half_mirror (xor 4)
        DPPADD(v[j], 0x140, 0xf);   // row_mirror      (xor 8)
        DPPADD(v[j], 0x142, 0xa);   // row_bcast:15 -> rows 1,3
        DPPADD(v[j], 0x143, 0xc);   // row_bcast:31 -> rows 2,3
    }
    if (lane == 63) {
        float best = v[0];
        #pragma unroll
        for (int j = 1; j < NJ; ++j) best = fminf(best, v[j]);
        atomicMin(sm, __float_as_uint(best));   // scores >= 0: uint order == float order
    }
}

template<int NBY, int NP>
__device__ __forceinline__ void proc(const __half2* __restrict__ winh, int (&addr)[4],
                                     const __half2 (&wx0)[4], const __half2 (&wx1)[4],
                                     const __half2 (&wy0n)[4], const __half2 (&wy1n)[4],
                                     const __half2 (&r1s)[4],
                                     unsigned* __restrict__ sm, int lane)
{
    __half2 hA[4][NP], hB[4][NP];
    rowload<NP>(winh, addr, wx0, wx1, hA);
    #pragma unroll
    for (int by = 0; by < NBY + 1; by += 2) {
        rowload<NP>(winh, addr, wx0, wx1, hB);
        bystep<NP>(hA, hB, wy0n, wy1n, r1s, sm, lane);
        if (by + 1 < NBY + 1) {
            rowload<NP>(winh, addr, wx0, wx1, hA);
            bystep<NP>(hB, hA, wy0n, wy1n, r1s, sm, lane);
        }
    }
}

// One block per image, 8 waves (512 threads): 4 blocks/CU x 8 waves = 32
// waves/CU (full occupancy; LDS 20.2KB allows 7 blocks, VGPR ~56 allows 8
// waves/SIMD). Item = (angle, sub), 18 per wave; window filled once per image.
__global__ __launch_bounds__(512) void randip_main(const float* __restrict__ fm1,
                                                   const float* __restrict__ fm2,
                                                   const uint4* __restrict__ gt,
                                                   float* __restrict__ out)
{
    __shared__ __half2 winh[WINSZH];    // 20160 B: pair c = (w[c-1], w[c]), f16
    __shared__ unsigned submin[16];

    const int b    = blockIdx.x;
    const int tid  = threadIdx.x;
    const int wave = tid >> 6;
    const int lane = tid & 63;

    for (int i = tid; i < WINSZH; i += 512) winh[i] = __floats2half2_rn(0.f, 0.f);
    if (tid < 16) submin[tid] = FLTMAX_BITS;
    __syncthreads();

    // fill pair-window: buffer (r+1, c) = (img2[r][c-1], img2[r][c])
    const float* img2 = fm2 + (size_t)b * 4096;
    for (int i = tid; i < 64 * 65; i += 512) {
        int r = i / 65, c = i - r * 65;
        float lo = (c >= 1)  ? img2[r * 64 + c - 1] : 0.f;
        float hi = (c <= 63) ? img2[r * 64 + c]     : 0.f;
        winh[(r + 1) * WSH + c] = __floats2half2_rn(lo, hi);
    }
    __syncthreads();

    const float* img1 = fm1 + (size_t)b * 4096;

    int a_cur = -1;
    __half2 wx0[4], wx1[4], wy0n[4], wy1n[4], r1s[4];
    float   sca[4];
    int     off[4];

    for (int i = wave * IPW; i < (wave + 1) * IPW; ++i) {
        const int a = i >> 4, sub = i & 15;
        if (a != a_cur) {                     // <=2 reloads per wave, coalesced b128
            a_cur = a;
            const uint4* tp = gt + a * NPIX + lane;
            #pragma unroll
            for (int k = 0; k < 4; ++k) {
                uint4 te = tp[64 * k];
                __half2 X = *(const __half2*)&te.x;
                __half2 Y = *(const __half2*)&te.y;
                wx0[k]  = __half2half2(__low2half(X));
                wx1[k]  = __half2half2(__high2half(X));
                wy0n[k] = __half2half2(__low2half(Y));
                wy1n[k] = __half2half2(__high2half(Y));
                sca[k]  = __uint_as_float(te.z);
                off[k]  = (int)te.w;
            }
        }
        const int sub_x = (sub & 3) << 4;
        const int sub_y = (sub >> 2) << 4;
        const int x_lo = max(sub_x - 4, 0);
        const int y_lo = max(sub_y - 4, 0);
        const int nvx = min(sub_x + 4, 48) - x_lo;   // 4 or 8
        const int nby = min(sub_y + 4, 48) - y_lo;   // 4 or 8
        const int rowbase0 = y_lo * WSH + x_lo;

        const float* r1p = img1 + (sub_y + (lane >> 4)) * 64 + sub_x + (lane & 15);
        #pragma unroll
        for (int k = 0; k < 4; ++k)
            r1s[k] = __float2half2_rn(sca[k] * r1p[k * 4 * 64]);

        int addr[4];
        #pragma unroll
        for (int k = 0; k < 4; ++k) addr[k] = rowbase0 + off[k];

        unsigned* sm = &submin[sub];
        if (nby == 8) {
            if (nvx == 8) proc<8, 5>(winh, addr, wx0, wx1, wy0n, wy1n, r1s, sm, lane);
            else          proc<8, 3>(winh, addr, wx0, wx1, wy0n, wy1n, r1s, sm, lane);
        } else {
            if (nvx == 8) proc<4, 5>(winh, addr, wx0, wx1, wy0n, wy1n, r1s, sm, lane);
            else          proc<4, 3>(winh, addr, wx0, wx1, wy0n, wy1n, r1s, sm, lane);
        }
    }
    __syncthreads();

    if (tid == 0) {
        float t = 0.0f;
        #pragma unroll
        for (int s = 0; s < 16; ++s) t += __uint_as_float(submin[s]);
        out[b] = t;
    }
}

extern "C" void kernel_launch(void* const* d_in, const int* in_sizes, int n_in,
                              void* d_out, int out_size, void* d_ws, size_t ws_size,
                              hipStream_t stream)
{
    const float* fm1 = (const float*)d_in[0];
    const float* fm2 = (const float*)d_in[1];
    float* out = (float*)d_out;
    uint4* tbl = (uint4*)d_ws;   // 36,864 B scratch

    const int nb = in_sizes[0] >> 12;   // 1024 images of 64*64

    hipLaunchKernelGGL(build_table, dim3(1), dim3(256), 0, stream, tbl);
    hipLaunchKernelGGL(randip_main, dim3(nb), dim3(512), 0, stream, fm1, fm2, tbl, out);
}